// Round 5
// baseline (636.008 us; speedup 1.0000x reference)
//
#include <hip/hip_runtime.h>

#define N_ROWS 65536
#define DIM 512       // NDIM == K == 512
#define MKNOTS 200
#define KT 16         // spline k-cols per block
#define NCELL 768     // cells over [-4,8], cell = 1/64; knot gap >= 0.0201 -> <=1 knot/cell
#define TILE 256      // spline rows per tile (= threads)
#define TPB 4         // tiles per block
#define NKT (DIM / KT)

typedef _Float16 f16x8 __attribute__((ext_vector_type(8)));
typedef _Float16 f16x4 __attribute__((ext_vector_type(4)));
typedef float f32x4 __attribute__((ext_vector_type(4)));

__device__ inline void gload16(const void* g, void* l) {
  __builtin_amdgcn_global_load_lds(
      (const __attribute__((address_space(1))) void*)g,
      (__attribute__((address_space(3))) void*)l,
      16, 0, 0);
}

// ---------------------------------------------------------------------------
// GEMM (baseline, unchanged — passing): C = A * Bt^T (+ addsrc), f16 MFMA,
// S3 = hi/lo split-3 for fp32-quality accumulation.
// ---------------------------------------------------------------------------
template <bool S3, bool ADDSRC>
__global__ __launch_bounds__(256)
void gemm_k(const _Float16* __restrict__ Ah, const _Float16* __restrict__ Al,
            const _Float16* __restrict__ Bth, const _Float16* __restrict__ Btl,
            const float* __restrict__ addsrc, float* __restrict__ C)
{
  __shared__ alignas(16) _Float16 smem[S3 ? 16384 : 8192];
  _Float16* sAh = smem;            // 128*32
  _Float16* sBh = smem + 4096;     // 128*32 (Bt rows = n)
  _Float16* sAl = S3 ? smem + 8192  : smem;
  _Float16* sBl = S3 ? smem + 12288 : smem;

  const int tid  = threadIdx.x;
  const int bm   = blockIdx.x * 128;
  const int bn   = blockIdx.y * 128;
  const int wm   = ((tid >> 6) >> 1) * 64;
  const int wn   = ((tid >> 6) & 1) * 64;
  const int lane = tid & 63;
  const int lm   = lane & 15;
  const int quad = lane >> 4;
  const int sr   = tid >> 2;        // staging row 0..63
  const int sc   = (tid & 3) * 8;   // staging col chunk (8 f16 = 16B)

  const _Float16* gAh = Ah  + (size_t)(bm + sr) * DIM + sc;
  const _Float16* gBh = Bth + (size_t)(bn + sr) * DIM + sc;
  const _Float16* gAl = S3 ? (Al  + (size_t)(bm + sr) * DIM + sc) : gAh;
  const _Float16* gBl = S3 ? (Btl + (size_t)(bn + sr) * DIM + sc) : gBh;

  f32x4 acc[4][4] = {};

  for (int k0 = 0; k0 < DIM; k0 += 32) {
    gload16(gAh + k0,               sAh + tid * 8);
    gload16(gAh + k0 + 64 * DIM,    sAh + 2048 + tid * 8);
    gload16(gBh + k0,               sBh + tid * 8);
    gload16(gBh + k0 + 64 * DIM,    sBh + 2048 + tid * 8);
    if constexpr (S3) {
      gload16(gAl + k0,             sAl + tid * 8);
      gload16(gAl + k0 + 64 * DIM,  sAl + 2048 + tid * 8);
      gload16(gBl + k0,             sBl + tid * 8);
      gload16(gBl + k0 + 64 * DIM,  sBl + 2048 + tid * 8);
    }
    __syncthreads();

    f16x8 a_h[4], b_h[4], a_l[4], b_l[4];
    #pragma unroll
    for (int i = 0; i < 4; ++i) {
      a_h[i] = *(const f16x8*)&sAh[(wm + i * 16 + lm) * 32 + quad * 8];
      b_h[i] = *(const f16x8*)&sBh[(wn + i * 16 + lm) * 32 + quad * 8];
      if constexpr (S3) {
        a_l[i] = *(const f16x8*)&sAl[(wm + i * 16 + lm) * 32 + quad * 8];
        b_l[i] = *(const f16x8*)&sBl[(wn + i * 16 + lm) * 32 + quad * 8];
      }
    }
    #pragma unroll
    for (int i = 0; i < 4; ++i)
      #pragma unroll
      for (int j = 0; j < 4; ++j) {
        acc[i][j] = __builtin_amdgcn_mfma_f32_16x16x32_f16(a_h[i], b_h[j], acc[i][j], 0, 0, 0);
        if constexpr (S3) {
          acc[i][j] = __builtin_amdgcn_mfma_f32_16x16x32_f16(a_h[i], b_l[j], acc[i][j], 0, 0, 0);
          acc[i][j] = __builtin_amdgcn_mfma_f32_16x16x32_f16(a_l[i], b_h[j], acc[i][j], 0, 0, 0);
        }
      }
    __syncthreads();
  }

  // C/D layout (verified m89/m91): col = lane&15, row = quad*4 + reg
  #pragma unroll
  for (int i = 0; i < 4; ++i)
    #pragma unroll
    for (int j = 0; j < 4; ++j)
      #pragma unroll
      for (int r = 0; r < 4; ++r) {
        const int row = bm + wm + i * 16 + quad * 4 + r;
        const int col = bn + wn + j * 16 + lm;
        const size_t idx = (size_t)row * DIM + col;
        float v = acc[i][j][r];
        if constexpr (ADDSRC) v += addsrc[idx];
        C[idx] = v;
      }
}

// ---------------------------------------------------------------------------
// fp32 -> f16 hi/lo split of data
// ---------------------------------------------------------------------------
__global__ __launch_bounds__(256)
void conv_data_k(const float* __restrict__ in, _Float16* __restrict__ hi,
                 _Float16* __restrict__ lo)
{
  const size_t i = ((size_t)blockIdx.x * 256 + threadIdx.x) * 4;
  const float4 v = *reinterpret_cast<const float4*>(in + i);
  f16x4 h, l;
  h.x = (_Float16)v.x; l.x = (_Float16)(v.x - (float)h.x);
  h.y = (_Float16)v.y; l.y = (_Float16)(v.y - (float)h.y);
  h.z = (_Float16)v.z; l.z = (_Float16)(v.z - (float)h.z);
  h.w = (_Float16)v.w; l.w = (_Float16)(v.w - (float)h.w);
  *reinterpret_cast<f16x4*>(hi + i) = h;
  *reinterpret_cast<f16x4*>(lo + i) = l;
}

__global__ __launch_bounds__(256)
void conv_A_k(const float* __restrict__ A, _Float16* __restrict__ Ah,
              _Float16* __restrict__ Al, _Float16* __restrict__ ATh,
              _Float16* __restrict__ ATl)
{
  const int i = blockIdx.x * 256 + threadIdx.x;
  const int r = i >> 9, c = i & 511;
  const float v = A[i];
  const _Float16 h = (_Float16)v;
  const _Float16 l = (_Float16)(v - (float)h);
  Ah[i] = h; Al[i] = l;
  ATh[c * 512 + r] = h; ATl[c * 512 + r] = l;
}

// ---------------------------------------------------------------------------
// Spline prep: pkG[k][j] = {x, y, d, 0}; bucketG[k][c] = #{x_j <= -4 + c/64}.
// Cell 1/64 = 0.015625 < min knot gap 0.0201 -> at most 1 knot per cell.
// ---------------------------------------------------------------------------
__global__ __launch_bounds__(256)
void prep_k(const float* __restrict__ xx, const float* __restrict__ yy,
            const float* __restrict__ dd, float4* __restrict__ pkG,
            unsigned char* __restrict__ bucketG)
{
  __shared__ float xr[MKNOTS];
  const int k = blockIdx.x, tid = threadIdx.x;
  if (tid < MKNOTS) xr[tid] = xx[k * MKNOTS + tid];
  __syncthreads();
  if (tid < MKNOTS) {
    const float x0 = xr[tid];
    const float y0 = yy[k * MKNOTS + tid];
    const float d0 = dd[k * MKNOTS + tid];
    pkG[k * MKNOTS + tid] = float4{x0, y0, d0, 0.f};
  }
  for (int c = tid; c < NCELL; c += 256) {
    const float cl = -4.f + (float)c * 0.015625f;
    int lo = 0, hi = MKNOTS;
    while (lo < hi) { const int mid = (lo + hi) >> 1; if (xr[mid] <= cl) lo = mid + 1; else hi = mid; }
    bucketG[k * NCELL + c] = (unsigned char)lo;
  }
}

// ---------------------------------------------------------------------------
// RQ spline v9: v8's byte-ideal I/O shell verbatim (FETCH 134MB / WRITE 74MB
// measured) with the eval loop restructured for latency-batching: all 16 xT
// reads hoisted to registers, all 16 bucket global gathers issued as one
// independent phase, math loop fully unrolled (static indexing -> registers)
// so many probe->gather chains overlap. z packed in registers, written as 8
// conflict-free b32 (bank = 17*tid+w mod 32 is a lane permutation).
// ---------------------------------------------------------------------------
__global__ __launch_bounds__(256, 3)
void spline_k(const float* __restrict__ data0, const float4* __restrict__ pkG,
              const unsigned char* __restrict__ bucketG,
              _Float16* __restrict__ zH, float* __restrict__ ppart)
{
  __shared__ float2 sXY[KT * 201];      // 25.7 KB: {x,y} per knot + 1 pad/row
  __shared__ _Float16 sD[KT * 201 + 2]; // 6.4 KB
  __shared__ float xT[TILE * 17];       // 17.4 KB: 16 x's + pad; z overwrites words 0..7

  const int kBase = blockIdx.x * KT;
  const int nBase = blockIdx.y * (TILE * TPB);
  const int tid = threadIdx.x;

  for (int i = tid; i < KT * MKNOTS; i += 256) {
    const int r = i / MKNOTS, c = i - r * MKNOTS;
    const float4 v = pkG[(kBase + r) * MKNOTS + c];
    sXY[r * 201 + c] = float2{v.x, v.y};
    sD[r * 201 + c] = (_Float16)v.z;
  }
  if (tid < KT) {                       // pad knot: read only when discarded
    sXY[tid * 201 + 200] = float2{1e30f, 0.f};
    sD[tid * 201 + 200] = (_Float16)1.f;
  }
  __syncthreads();

  for (int tile = 0; tile < TPB; ++tile) {
    const int n0 = nBase + tile * TILE;

    // stage x tile: full-line coalesced (4 lanes x float4 per row) [amp-free]
    #pragma unroll
    for (int rr = 0; rr < 4; ++rr) {
      const int r = rr * 64 + (tid >> 2);
      const float4 v = *((const float4*)(data0 + (size_t)(n0 + r) * DIM + kBase) + (tid & 3));
      float* dst = &xT[r * 17 + (tid & 3) * 4];
      dst[0] = v.x; dst[1] = v.y; dst[2] = v.z; dst[3] = v.w;
    }
    __syncthreads();

    // phase 0: own row -> registers (16 independent ds_read_b32)
    float xv[KT];
    #pragma unroll
    for (int j = 0; j < KT; ++j) xv[j] = xT[tid * 17 + j];

    // phase 1: all bucket gathers in flight together (16 independent loads)
    int cnt[KT];
    #pragma unroll
    for (int j = 0; j < KT; ++j) {
      int c = (int)(xv[j] * 64.f + 256.f);   // floor((x+4)*64) for x > -4
      c = min(max(c, 0), NCELL - 1);
      cnt[j] = (int)bucketG[(kBase + j) * NCELL + c];  // #knots <= cell-left, >=1
    }

    // phase 2: fully-unrolled evals; probe->gather chains of many j overlap
    float acc = 0.f;
    float zprev = 0.f;
    unsigned int zw[KT / 2];
    #pragma unroll
    for (int j = 0; j < KT; ++j) {
      const float x = xv[j];
      const int q = min(cnt[j], MKNOTS - 1);
      const float xq = sXY[j * 201 + q].x;          // <=1 knot/cell -> 1 cmp refine
      const int b = min(cnt[j] + (xq < x ? 1 : 0), MKNOTS) - 1;  // searchsorted-1

      const float2 p0 = sXY[j * 201 + b];           // {xk, yk}
      const float2 p1 = sXY[j * 201 + b + 1];       // {xk1, yk1}
      const float dk  = (float)sD[j * 201 + b];
      const float dk1 = (float)sD[j * 201 + b + 1];

      const float rdx = __builtin_amdgcn_rcpf(p1.x - p0.x);
      const float dy  = p1.y - p0.y;
      const float s   = dy * rdx;
      float xi = (x - p0.x) * rdx;
      xi = fminf(fmaxf(xi, 0.f), 1.f);
      const float xi1 = 1.f - xi;
      const float g = xi * xi1;
      const float den = s + (dk1 + dk - 2.f * s) * g;
      const float rden = __builtin_amdgcn_rcpf(den);
      const float y_in = p0.y + dy * (s * xi * xi + dk * g) * rden;
      const float dnum = dk1 * xi * xi + 2.f * s * g + dk * xi1 * xi1;

      const bool edge = (x <= -4.f) || (b == MKNOTS - 1);  // below || above
      const float larg = edge ? dk : (s * s * dnum) * (rden * rden);
      acc += __logf(larg);                                  // single transcendental
      const float y = edge ? (p0.y + dk * (x - p0.x)) : y_in;

      const float z = y - x;
      if (j & 1) {
        union { _Float16 h[2]; unsigned int u; } pk2;
        pk2.h[0] = (_Float16)zprev; pk2.h[1] = (_Float16)z;
        zw[j >> 1] = pk2.u;
      } else {
        zprev = z;
      }
    }

    // phase 3: z words -> xT (bank-permutation across lanes: conflict-free)
    #pragma unroll
    for (int w = 0; w < 8; ++w)
      ((unsigned int*)xT)[tid * 17 + w] = zw[w];

    ppart[(size_t)blockIdx.x * N_ROWS + n0 + tid] = acc;
    __syncthreads();

    // coop z store: 8 lanes x 4B cover a row's 32B contiguous (baseline shape)
    const int w = tid & 7;
    #pragma unroll
    for (int ri = 0; ri < 8; ++ri) {
      const int r = ri * 32 + (tid >> 3);
      const unsigned int zz = ((const unsigned int*)xT)[r * 17 + w];
      *(unsigned int*)(zH + (size_t)(n0 + r) * DIM + kBase + w * 2) = zz;
    }
    __syncthreads();
  }
}

// logj[n] = sum over NKT k-tiles of ppart[kt][n]
__global__ __launch_bounds__(256)
void reduce_k(const float* __restrict__ ppart, float* __restrict__ logj)
{
  const int n = blockIdx.x * 256 + threadIdx.x;
  float a = 0.f;
  #pragma unroll
  for (int t = 0; t < NKT; ++t) a += ppart[(size_t)t * N_ROWS + n];
  logj[n] = a;
}

// ---------------------------------------------------------------------------
extern "C" void kernel_launch(void* const* d_in, const int* in_sizes, int n_in,
                              void* d_out, int out_size, void* d_ws, size_t ws_size,
                              hipStream_t stream)
{
  const float* data  = (const float*)d_in[0];
  const float* A     = (const float*)d_in[1];
  const float* xx    = (const float*)d_in[2];
  const float* yy    = (const float*)d_in[3];
  const float* delta = (const float*)d_in[4];

  float* out  = (float*)d_out;                       // N_ROWS * DIM
  float* logj = out + (size_t)N_ROWS * DIM;          // N_ROWS

  // workspace layout (~258 MiB)
  _Float16* dHi = (_Float16*)d_ws;                   // 64 MiB
  _Float16* dLo = dHi + (size_t)N_ROWS * DIM;        // 64 MiB
  _Float16* Ah  = dLo + (size_t)N_ROWS * DIM;        // 512 KiB each
  _Float16* Al  = Ah + 512 * 512;
  _Float16* ATh = Al + 512 * 512;
  _Float16* ATl = ATh + 512 * 512;
  float* data0  = (float*)(ATl + 512 * 512);         // 128 MiB
  _Float16* zH  = dHi;                               // alias: dHi dead after GEMM1
  // spline tables + partials alias dLo (dead after GEMM1): 1.6M + 384K + 8M
  float4* pkG = (float4*)dLo;
  unsigned char* bucketG = (unsigned char*)(pkG + 512 * MKNOTS);
  float* ppart = (float*)(bucketG + 512 * NCELL);

  conv_A_k<<<1024, 256, 0, stream>>>(A, Ah, Al, ATh, ATl);
  conv_data_k<<<(N_ROWS * DIM) / (256 * 4), 256, 0, stream>>>(data, dHi, dLo);

  // data0 = data @ A  (split-3 f16, fp32-quality)
  gemm_k<true, false><<<dim3(N_ROWS / 128, DIM / 128), 256, 0, stream>>>(
      dHi, dLo, ATh, ATl, nullptr, data0);

  prep_k<<<512, 256, 0, stream>>>(xx, yy, delta, pkG, bucketG);

  spline_k<<<dim3(DIM / KT, N_ROWS / (TILE * TPB)), 256, 0, stream>>>(
      data0, pkG, bucketG, zH, ppart);

  reduce_k<<<N_ROWS / 256, 256, 0, stream>>>(ppart, logj);

  // out = data + z @ A^T  (plain f16)
  gemm_k<false, true><<<dim3(N_ROWS / 128, DIM / 128), 256, 0, stream>>>(
      zH, nullptr, Ah, nullptr, data, out);
}

// Round 6
// 588.621 us; speedup vs baseline: 1.0805x; 1.0805x over previous
//
#include <hip/hip_runtime.h>

#define N_ROWS 65536
#define DIM 512       // NDIM == K == 512
#define MKNOTS 200
#define KT 16         // spline k-cols per block
#define NCELL 768     // cells over [-4,8], cell = 1/64; knot gap >= 0.0201 -> <=1 knot/cell
#define TILE 512      // spline rows per tile (= threads)
#define TPB 2         // tiles per block (coverage = 1024 rows, same as v8)
#define NKT (DIM / KT)

typedef _Float16 f16x8 __attribute__((ext_vector_type(8)));
typedef _Float16 f16x4 __attribute__((ext_vector_type(4)));
typedef float f32x4 __attribute__((ext_vector_type(4)));

__device__ inline void gload16(const void* g, void* l) {
  __builtin_amdgcn_global_load_lds(
      (const __attribute__((address_space(1))) void*)g,
      (__attribute__((address_space(3))) void*)l,
      16, 0, 0);
}

// ---------------------------------------------------------------------------
// GEMM (baseline structure — passing): C = A * Bt^T (+ addsrc), f16 MFMA,
// S3 = hi/lo split-3 for fp32-quality accumulation.
// v10: blockIdx axes swapped (x = N-block, fast-varying) so the 4 col-blocks
// sharing a 128-row panel of the big A operand run back-to-back -> panel
// re-reads hit L2/L3 instead of streaming 4x from HBM.
// ---------------------------------------------------------------------------
template <bool S3, bool ADDSRC>
__global__ __launch_bounds__(256)
void gemm_k(const _Float16* __restrict__ Ah, const _Float16* __restrict__ Al,
            const _Float16* __restrict__ Bth, const _Float16* __restrict__ Btl,
            const float* __restrict__ addsrc, float* __restrict__ C)
{
  __shared__ alignas(16) _Float16 smem[S3 ? 16384 : 8192];
  _Float16* sAh = smem;            // 128*32
  _Float16* sBh = smem + 4096;     // 128*32 (Bt rows = n)
  _Float16* sAl = S3 ? smem + 8192  : smem;
  _Float16* sBl = S3 ? smem + 12288 : smem;

  const int tid  = threadIdx.x;
  const int bm   = blockIdx.y * 128;   // M-block: slow axis
  const int bn   = blockIdx.x * 128;   // N-block: fast axis (L3 reuse of A-panel)
  const int wm   = ((tid >> 6) >> 1) * 64;
  const int wn   = ((tid >> 6) & 1) * 64;
  const int lane = tid & 63;
  const int lm   = lane & 15;
  const int quad = lane >> 4;
  const int sr   = tid >> 2;        // staging row 0..63
  const int sc   = (tid & 3) * 8;   // staging col chunk (8 f16 = 16B)

  const _Float16* gAh = Ah  + (size_t)(bm + sr) * DIM + sc;
  const _Float16* gBh = Bth + (size_t)(bn + sr) * DIM + sc;
  const _Float16* gAl = S3 ? (Al  + (size_t)(bm + sr) * DIM + sc) : gAh;
  const _Float16* gBl = S3 ? (Btl + (size_t)(bn + sr) * DIM + sc) : gBh;

  f32x4 acc[4][4] = {};

  for (int k0 = 0; k0 < DIM; k0 += 32) {
    gload16(gAh + k0,               sAh + tid * 8);
    gload16(gAh + k0 + 64 * DIM,    sAh + 2048 + tid * 8);
    gload16(gBh + k0,               sBh + tid * 8);
    gload16(gBh + k0 + 64 * DIM,    sBh + 2048 + tid * 8);
    if constexpr (S3) {
      gload16(gAl + k0,             sAl + tid * 8);
      gload16(gAl + k0 + 64 * DIM,  sAl + 2048 + tid * 8);
      gload16(gBl + k0,             sBl + tid * 8);
      gload16(gBl + k0 + 64 * DIM,  sBl + 2048 + tid * 8);
    }
    __syncthreads();

    f16x8 a_h[4], b_h[4], a_l[4], b_l[4];
    #pragma unroll
    for (int i = 0; i < 4; ++i) {
      a_h[i] = *(const f16x8*)&sAh[(wm + i * 16 + lm) * 32 + quad * 8];
      b_h[i] = *(const f16x8*)&sBh[(wn + i * 16 + lm) * 32 + quad * 8];
      if constexpr (S3) {
        a_l[i] = *(const f16x8*)&sAl[(wm + i * 16 + lm) * 32 + quad * 8];
        b_l[i] = *(const f16x8*)&sBl[(wn + i * 16 + lm) * 32 + quad * 8];
      }
    }
    #pragma unroll
    for (int i = 0; i < 4; ++i)
      #pragma unroll
      for (int j = 0; j < 4; ++j) {
        acc[i][j] = __builtin_amdgcn_mfma_f32_16x16x32_f16(a_h[i], b_h[j], acc[i][j], 0, 0, 0);
        if constexpr (S3) {
          acc[i][j] = __builtin_amdgcn_mfma_f32_16x16x32_f16(a_h[i], b_l[j], acc[i][j], 0, 0, 0);
          acc[i][j] = __builtin_amdgcn_mfma_f32_16x16x32_f16(a_l[i], b_h[j], acc[i][j], 0, 0, 0);
        }
      }
    __syncthreads();
  }

  // C/D layout (verified m89/m91): col = lane&15, row = quad*4 + reg
  #pragma unroll
  for (int i = 0; i < 4; ++i)
    #pragma unroll
    for (int j = 0; j < 4; ++j)
      #pragma unroll
      for (int r = 0; r < 4; ++r) {
        const int row = bm + wm + i * 16 + quad * 4 + r;
        const int col = bn + wn + j * 16 + lm;
        const size_t idx = (size_t)row * DIM + col;
        float v = acc[i][j][r];
        if constexpr (ADDSRC) v += addsrc[idx];
        C[idx] = v;
      }
}

// ---------------------------------------------------------------------------
// fp32 -> f16 hi/lo split of data
// ---------------------------------------------------------------------------
__global__ __launch_bounds__(256)
void conv_data_k(const float* __restrict__ in, _Float16* __restrict__ hi,
                 _Float16* __restrict__ lo)
{
  const size_t i = ((size_t)blockIdx.x * 256 + threadIdx.x) * 4;
  const float4 v = *reinterpret_cast<const float4*>(in + i);
  f16x4 h, l;
  h.x = (_Float16)v.x; l.x = (_Float16)(v.x - (float)h.x);
  h.y = (_Float16)v.y; l.y = (_Float16)(v.y - (float)h.y);
  h.z = (_Float16)v.z; l.z = (_Float16)(v.z - (float)h.z);
  h.w = (_Float16)v.w; l.w = (_Float16)(v.w - (float)h.w);
  *reinterpret_cast<f16x4*>(hi + i) = h;
  *reinterpret_cast<f16x4*>(lo + i) = l;
}

__global__ __launch_bounds__(256)
void conv_A_k(const float* __restrict__ A, _Float16* __restrict__ Ah,
              _Float16* __restrict__ Al, _Float16* __restrict__ ATh,
              _Float16* __restrict__ ATl)
{
  const int i = blockIdx.x * 256 + threadIdx.x;
  const int r = i >> 9, c = i & 511;
  const float v = A[i];
  const _Float16 h = (_Float16)v;
  const _Float16 l = (_Float16)(v - (float)h);
  Ah[i] = h; Al[i] = l;
  ATh[c * 512 + r] = h; ATl[c * 512 + r] = l;
}

// ---------------------------------------------------------------------------
// Spline prep: pkG[k][j] = {x, y, d, 0}; bucketG[k][c] = #{x_j <= -4 + c/64}.
// Cell 1/64 = 0.015625 < min knot gap 0.0201 -> at most 1 knot per cell.
// ---------------------------------------------------------------------------
__global__ __launch_bounds__(256)
void prep_k(const float* __restrict__ xx, const float* __restrict__ yy,
            const float* __restrict__ dd, float4* __restrict__ pkG,
            unsigned char* __restrict__ bucketG)
{
  __shared__ float xr[MKNOTS];
  const int k = blockIdx.x, tid = threadIdx.x;
  if (tid < MKNOTS) xr[tid] = xx[k * MKNOTS + tid];
  __syncthreads();
  if (tid < MKNOTS) {
    const float x0 = xr[tid];
    const float y0 = yy[k * MKNOTS + tid];
    const float d0 = dd[k * MKNOTS + tid];
    pkG[k * MKNOTS + tid] = float4{x0, y0, d0, 0.f};
  }
  for (int c = tid; c < NCELL; c += 256) {
    const float cl = -4.f + (float)c * 0.015625f;
    int lo = 0, hi = MKNOTS;
    while (lo < hi) { const int mid = (lo + hi) >> 1; if (xr[mid] <= cl) lo = mid + 1; else hi = mid; }
    bucketG[k * NCELL + c] = (unsigned char)lo;
  }
}

// ---------------------------------------------------------------------------
// RQ spline v10: v8's proven body and byte-ideal I/O shapes (FETCH 134MB /
// WRITE 74MB measured), reshaped to 512-thread blocks for occupancy:
// TILE=512, TPB=2 -> same 1024-row coverage, same per-WAVE instruction
// shapes (stage = 16 rows x 64B full lines; coop store = 8 rows x 32B), but
// LDS 67KB -> 2 blocks x 8 waves = 16 waves/CU (was 12). launch_bounds
// (512,4) caps VGPR at 128 (kernel ~70 -> no spill; v9's lesson: no big
// per-thread arrays, keep interleaved unroll-4 eval).
// ---------------------------------------------------------------------------
__global__ __launch_bounds__(512, 4)
void spline_k(const float* __restrict__ data0, const float4* __restrict__ pkG,
              const unsigned char* __restrict__ bucketG,
              _Float16* __restrict__ zH, float* __restrict__ ppart)
{
  __shared__ float2 sXY[KT * 201];      // 25.7 KB: {x,y} per knot + 1 pad/row
  __shared__ _Float16 sD[KT * 201 + 2]; // 6.4 KB
  __shared__ float xT[TILE * 17];       // 34.8 KB: 16 x's + pad; z overwrites words 0..7

  const int kBase = blockIdx.x * KT;
  const int nBase = blockIdx.y * (TILE * TPB);
  const int tid = threadIdx.x;

  for (int i = tid; i < KT * MKNOTS; i += 512) {
    const int r = i / MKNOTS, c = i - r * MKNOTS;
    const float4 v = pkG[(kBase + r) * MKNOTS + c];
    sXY[r * 201 + c] = float2{v.x, v.y};
    sD[r * 201 + c] = (_Float16)v.z;
  }
  if (tid < KT) {                       // pad knot: read only when discarded
    sXY[tid * 201 + 200] = float2{1e30f, 0.f};
    sD[tid * 201 + 200] = (_Float16)1.f;
  }
  __syncthreads();

  for (int tile = 0; tile < TPB; ++tile) {
    const int n0 = nBase + tile * TILE;

    // stage x tile: full-line coalesced (4 lanes x float4 per row) [amp-free]
    #pragma unroll
    for (int rr = 0; rr < 4; ++rr) {
      const int r = rr * 128 + (tid >> 2);
      const float4 v = *((const float4*)(data0 + (size_t)(n0 + r) * DIM + kBase) + (tid & 3));
      float* dst = &xT[r * 17 + (tid & 3) * 4];
      dst[0] = v.x; dst[1] = v.y; dst[2] = v.z; dst[3] = v.w;
    }
    __syncthreads();

    // compute: thread -> row n0+tid, 16 evals, register logd accumulation
    float acc = 0.f;
    float zprev = 0.f;
    #pragma unroll 4
    for (int j = 0; j < KT; ++j) {
      const float x = xT[tid * 17 + j];

      int c = (int)(x * 64.f + 256.f);  // floor((x+4)*64) for x > -4
      c = min(max(c, 0), NCELL - 1);
      const int cnt = (int)bucketG[(kBase + j) * NCELL + c];  // #knots <= cell-left, >=1
      const int q = min(cnt, MKNOTS - 1);
      const float xq = sXY[j * 201 + q].x;          // <=1 knot/cell -> 1 cmp refine
      const int b = min(cnt + (xq < x ? 1 : 0), MKNOTS) - 1;  // searchsorted-1, 0..199

      const float2 p0 = sXY[j * 201 + b];           // {xk, yk}
      const float2 p1 = sXY[j * 201 + b + 1];       // {xk1, yk1}
      const float dk  = (float)sD[j * 201 + b];
      const float dk1 = (float)sD[j * 201 + b + 1];

      const float rdx = __builtin_amdgcn_rcpf(p1.x - p0.x);
      const float dy  = p1.y - p0.y;
      const float s   = dy * rdx;
      float xi = (x - p0.x) * rdx;
      xi = fminf(fmaxf(xi, 0.f), 1.f);
      const float xi1 = 1.f - xi;
      const float g = xi * xi1;
      const float den = s + (dk1 + dk - 2.f * s) * g;
      const float rden = __builtin_amdgcn_rcpf(den);
      const float y_in = p0.y + dy * (s * xi * xi + dk * g) * rden;
      const float dnum = dk1 * xi * xi + 2.f * s * g + dk * xi1 * xi1;

      const bool edge = (x <= -4.f) || (b == MKNOTS - 1);  // below || above
      const float larg = edge ? dk : (s * s * dnum) * (rden * rden);
      acc += __logf(larg);                                  // single transcendental
      const float y = edge ? (p0.y + dk * (x - p0.x)) : y_in;

      const float z = y - x;
      if (j & 1) {
        union { _Float16 h[2]; unsigned int u; } pk2;
        pk2.h[0] = (_Float16)zprev; pk2.h[1] = (_Float16)z;
        ((unsigned int*)xT)[tid * 17 + (j >> 1)] = pk2.u;   // word (j>>1) < j: safe in-place
      } else {
        zprev = z;
      }
    }
    ppart[(size_t)blockIdx.x * N_ROWS + n0 + tid] = acc;
    __syncthreads();

    // coop z store: 8 lanes x 4B cover a row's 32B contiguous (proven shape)
    const int w = tid & 7;
    #pragma unroll
    for (int ri = 0; ri < 8; ++ri) {
      const int r = ri * 64 + (tid >> 3);
      const unsigned int zz = ((const unsigned int*)xT)[r * 17 + w];
      *(unsigned int*)(zH + (size_t)(n0 + r) * DIM + kBase + w * 2) = zz;
    }
    __syncthreads();
  }
}

// logj[n] = sum over NKT k-tiles of ppart[kt][n]
__global__ __launch_bounds__(256)
void reduce_k(const float* __restrict__ ppart, float* __restrict__ logj)
{
  const int n = blockIdx.x * 256 + threadIdx.x;
  float a = 0.f;
  #pragma unroll
  for (int t = 0; t < NKT; ++t) a += ppart[(size_t)t * N_ROWS + n];
  logj[n] = a;
}

// ---------------------------------------------------------------------------
extern "C" void kernel_launch(void* const* d_in, const int* in_sizes, int n_in,
                              void* d_out, int out_size, void* d_ws, size_t ws_size,
                              hipStream_t stream)
{
  const float* data  = (const float*)d_in[0];
  const float* A     = (const float*)d_in[1];
  const float* xx    = (const float*)d_in[2];
  const float* yy    = (const float*)d_in[3];
  const float* delta = (const float*)d_in[4];

  float* out  = (float*)d_out;                       // N_ROWS * DIM
  float* logj = out + (size_t)N_ROWS * DIM;          // N_ROWS

  // workspace layout (~258 MiB)
  _Float16* dHi = (_Float16*)d_ws;                   // 64 MiB
  _Float16* dLo = dHi + (size_t)N_ROWS * DIM;        // 64 MiB
  _Float16* Ah  = dLo + (size_t)N_ROWS * DIM;        // 512 KiB each
  _Float16* Al  = Ah + 512 * 512;
  _Float16* ATh = Al + 512 * 512;
  _Float16* ATl = ATh + 512 * 512;
  float* data0  = (float*)(ATl + 512 * 512);         // 128 MiB
  _Float16* zH  = dHi;                               // alias: dHi dead after GEMM1
  // spline tables + partials alias dLo (dead after GEMM1): 1.6M + 384K + 8M
  float4* pkG = (float4*)dLo;
  unsigned char* bucketG = (unsigned char*)(pkG + 512 * MKNOTS);
  float* ppart = (float*)(bucketG + 512 * NCELL);

  conv_A_k<<<1024, 256, 0, stream>>>(A, Ah, Al, ATh, ATl);
  conv_data_k<<<(N_ROWS * DIM) / (256 * 4), 256, 0, stream>>>(data, dHi, dLo);

  // data0 = data @ A  (split-3 f16, fp32-quality); x = N-block fast for L3 reuse
  gemm_k<true, false><<<dim3(DIM / 128, N_ROWS / 128), 256, 0, stream>>>(
      dHi, dLo, ATh, ATl, nullptr, data0);

  prep_k<<<512, 256, 0, stream>>>(xx, yy, delta, pkG, bucketG);

  spline_k<<<dim3(DIM / KT, N_ROWS / (TILE * TPB)), 512, 0, stream>>>(
      data0, pkG, bucketG, zH, ppart);

  reduce_k<<<N_ROWS / 256, 256, 0, stream>>>(ppart, logj);

  // out = data + z @ A^T  (plain f16); x = N-block fast for L3 reuse of zH
  gemm_k<false, true><<<dim3(DIM / 128, N_ROWS / 128), 256, 0, stream>>>(
      zH, nullptr, Ah, nullptr, data, out);
}